// Round 14
// baseline (266.853 us; speedup 1.0000x reference)
//
#include <hip/hip_runtime.h>
#include <math.h>

#define N_ROWS 32768
#define DIM 64
#define KCOMP 64
#define KSPLIT 8
#define KLOCAL 8           // KCOMP / KSPLIT
#define THREADS 256        // 4 waves
#define PREP_THREADS 256
#define RT 4               // row-tiles of 16 per wave
#define ROWS_PER_WAVE 64
#define ROWS_PER_BLOCK 256 // 4 waves * 64 rows
#define ROWGROUPS (N_ROWS / ROWS_PER_BLOCK)   // 128

// Pt layout per k (16384 B total, no padding):
//   for et in 0..4, c in 0..2:  block of 2048 B at (et*2+c)*2048:
//     [hi: 64 chunks x 16 B, chunk index = lane = q*16+m]
//     [lo: same, +1024]
//   chunk(lane) holds f16 P[d = c*32 + q*8 + j][e = et*16 + m], j=0..7
#define PT_K_BYTES 16384

#define LOG2PI_D 1.8378770664093454836

typedef _Float16 f16x8 __attribute__((ext_vector_type(8)));
typedef float f32x4 __attribute__((ext_vector_type(4)));

#define AS1 __attribute__((address_space(1)))
#define AS3 __attribute__((address_space(3)))

// async 16B/lane global->LDS DMA: lds dest wave-uniform; lane i -> base+i*16
__device__ __forceinline__ void async_copy16(const char* g, char* l) {
  __builtin_amdgcn_global_load_lds((const AS1 unsigned int*)g,
                                   (AS3 unsigned int*)l, 16, 0, 0);
}

// ---------------- digamma (double, recurrence + asymptotic) ----------------
__device__ __forceinline__ double digamma_d(double x) {
  double r = 0.0;
  while (x < 6.0) { r -= 1.0 / x; x += 1.0; }
  double inv = 1.0 / x;
  double inv2 = inv * inv;
  double s = log(x) - 0.5 * inv
      - inv2 * (1.0/12.0 - inv2 * (1.0/120.0 - inv2 * (1.0/252.0
      - inv2 * (1.0/240.0 - inv2 * (1.0/132.0)))));
  return r + s;
}

// ------- prep1: one block per k. LDS-staged transpose repack of P into Pt.
//         Wave 0: muP, log-det, digamma sums, stick-breaking terms.
//         Also zeroes packed/cnt (fused memset -> one fewer graph node). ----
__global__ void prep1_kernel(const float* __restrict__ means,
                             const float* __restrict__ P,
                             const float* __restrict__ wc,
                             const float* __restrict__ dof,
                             const float* __restrict__ mp,
                             char*   __restrict__ Pt,
                             float*  __restrict__ muP,
                             double* __restrict__ t_arr,
                             double* __restrict__ g_arr,
                             double* __restrict__ pc_arr,
                             uint4*  __restrict__ packed4,  // 16384 x 16 B
                             uint4*  __restrict__ cnt4)     // 64 x 16 B
{
  __shared__ float lds[DIM][DIM + 1];
  const int k = blockIdx.x;
  const int t = threadIdx.x;
  const float* Pk = P + k * DIM * DIM;

  // fused memset: zero packed (64 blk x 256 thr x 16 B = 256 KB) + cnt
  const uint4 z4 = {0u, 0u, 0u, 0u};
  packed4[k * PREP_THREADS + t] = z4;
  if (k == 0 && t < 64) cnt4[t] = z4;

  for (int i = t; i < DIM * DIM; i += PREP_THREADS)
    lds[i >> 6][i & 63] = Pk[i];
  __syncthreads();

  char* dst = Pt + (size_t)k * PT_K_BYTES;
#pragma unroll
  for (int cc = 0; cc < 4; ++cc) {
    int cid  = cc * PREP_THREADS + t;
    int blk  = cid >> 7;               // et*2 + c
    int sel  = (cid >> 6) & 1;         // 0=hi 1=lo
    int lane = cid & 63;
    int et = blk >> 1, c = blk & 1;
    int m = lane & 15, q = lane >> 4;
    int e = et * 16 + m;
    int d0 = c * 32 + q * 8;
    f16x8 o;
#pragma unroll
    for (int j = 0; j < 8; ++j) {
      float v = lds[d0 + j][e];
      _Float16 h = (_Float16)v;
      o[j] = sel ? (_Float16)(v - (float)h) : h;
    }
    *(f16x8*)(dst + cid * 16) = o;
  }

  if (t < 64) {
    const int i = t;
    const float* mk = means + k * DIM;
    float acc = 0.f;
#pragma unroll 8
    for (int d = 0; d < DIM; ++d) acc = fmaf(mk[d], lds[d][i], acc);
    muP[k * DIM + i] = acc;

    double dofk = (double)dof[k];
    double s1 = digamma_d(0.5 * (dofk - (double)i));
    double s2 = log((double)lds[i][i]);
#pragma unroll
    for (int off = 32; off > 0; off >>= 1) {
      s1 += __shfl_down(s1, off);
      s2 += __shfl_down(s2, off);
    }
    if (i == 0) {
      double ak = (double)wc[k], bk = (double)wc[KCOMP + k];
      double dgab = digamma_d(ak + bk);
      double log_lambda = (double)DIM * log(2.0) + s1;
      double pc = s2
                - 0.5 * (double)DIM * LOG2PI_D
                - 0.5 * (double)DIM * log(dofk)
                + 0.5 * (log_lambda - (double)DIM / (double)mp[k]);
      t_arr[k] = digamma_d(bk) - dgab;
      g_arr[k] = digamma_d(ak) - dgab;
      pc_arr[k] = pc;
    }
  }
}

// -------- main: f16-split MFMA, 4 row-tiles/wave, double-buffered LDS B via
//          async global_load_lds. Fold epilogue SOFTWARE-PIPELINED: k's 4
//          fold stages execute one-per-et-phase of k+1's MFMA block, hiding
//          shuffle latency under matrix work. Fused argmax via device-scope
//          atomics, NO fences (R8: fences = cache-wide L2 maintenance). -----
__global__ __launch_bounds__(THREADS, 4) void main_kernel(
    const float* __restrict__ X,
    const char*  __restrict__ Pt,
    const float* __restrict__ muP,
    const double* __restrict__ t_arr,
    const double* __restrict__ g_arr,
    const double* __restrict__ pc_arr,
    unsigned long long* __restrict__ packed,  // [N_ROWS], zeroed by prep1
    int* __restrict__ cnt,                    // [ROWGROUPS], zeroed by prep1
    int* __restrict__ out)
{
  __shared__ uint4 bbuf[2][PT_K_BYTES / 16];  // 2 x 16 KB B double-buffer
  __shared__ float cvec_lds[KCOMP];
  __shared__ float mup_lds[KLOCAL * DIM];
  __shared__ int is_last;

  const int tid  = threadIdx.x;
  const int wave = tid >> 6;           // 0..3
  const int lane = tid & 63;
  const int m    = lane & 15;          // MFMA row (A) / col (B) index
  const int q    = lane >> 4;          // quad
  const int ks   = blockIdx.y;
  const int rowbase = blockIdx.x * ROWS_PER_BLOCK + wave * ROWS_PER_WAVE;
  const int k0   = ks * KLOCAL;

  // ---- kick off async stage of k0's B image into buf 0 (4 DMA insts/wave) --
  {
    const char* src = Pt + (size_t)k0 * PT_K_BYTES;
#pragma unroll
    for (int i = 0; i < 4; ++i) {
      const int g = wave * 4 + i;                    // 1 KB group, uniform/wave
      async_copy16(src + (g << 10) + (lane << 4),
                   (char*)&bbuf[0][g << 6]);
    }
  }

  // wave 0: stick-breaking prefix -> cvec in LDS (6 shuffles)
  if (tid < 64) {
    double t = t_arr[tid];
    double s = t;
#pragma unroll
    for (int off = 1; off < 64; off <<= 1) {
      double v = __shfl_up(s, off);
      if (tid >= off) s += v;
    }
    cvec_lds[tid] = (float)(pc_arr[tid] + g_arr[tid] + (s - t));
  }
  // stage this block's muP slice: [k_local][e], coalesced
  for (int i = tid; i < KLOCAL * DIM; i += THREADS)
    mup_lds[i] = muP[ks * KLOCAL * DIM + i];

  // ---- load + split X rows into register-resident A fragments (4 tiles) ----
  f16x8 ahi[RT][2], alo[RT][2];
#pragma unroll
  for (int rt = 0; rt < RT; ++rt) {
    int row = rowbase + rt * 16 + m;
    const float* xp = X + row * DIM;
#pragma unroll
    for (int c = 0; c < 2; ++c) {
      const float4* xq4 = (const float4*)(xp + c * 32 + q * 8);
      float4 v0 = xq4[0], v1 = xq4[1];
      float xv[8] = {v0.x, v0.y, v0.z, v0.w, v1.x, v1.y, v1.z, v1.w};
      f16x8 h, l;
#pragma unroll
      for (int j = 0; j < 8; ++j) {
        _Float16 hv = (_Float16)xv[j];
        h[j] = hv;
        l[j] = (_Float16)(xv[j] - (float)hv);
      }
      ahi[rt][c] = h;
      alo[rt][c] = l;
    }
  }

  __syncthreads();   // buf0 DMA drained (vmcnt) + cvec/mup visible

  float best = -INFINITY;
  int   bidx = 0;
  const bool b0 = (m & 1), b1 = (m & 2), b2 = (m & 4), b3 = (m & 8);

  // pipelined-fold state for the previous k
  float sqp[16];
  float fv8[8], fv4[4], fv2[2];
  float ckp = 0.f;
  int   kprev = 0;

  for (int ki = 0; ki < KLOCAL; ++ki) {
    const int k = k0 + ki;
    const int p = ki & 1;

    // async stage next k's B into the other buffer (lands during compute)
    if (ki + 1 < KLOCAL) {
      const char* src = Pt + (size_t)(k + 1) * PT_K_BYTES;
#pragma unroll
      for (int i = 0; i < 4; ++i) {
        const int g = wave * 4 + i;
        async_copy16(src + (g << 10) + (lane << 4),
                     (char*)&bbuf[1 - p][g << 6]);
      }
    }

    const char* lb = (const char*)bbuf[p];
    const float ck = cvec_lds[k];
    float sq[16];
#pragma unroll
    for (int i = 0; i < 16; ++i) sq[i] = 0.f;      // idx = rt*4 + r

#pragma unroll
    for (int et = 0; et < 4; ++et) {
      const float mval = -mup_lds[(ki << 6) + et * 16 + m];
      f32x4 acc[RT];
#pragma unroll
      for (int rt = 0; rt < RT; ++rt)
#pragma unroll
        for (int r = 0; r < 4; ++r) acc[rt][r] = mval;

      // ---- pipelined fold: stage `et` of previous k's reduction ----
      if (ki > 0) {
        if (et == 0) {
#pragma unroll
          for (int pp = 0; pp < 8; ++pp) {
            float keep = b0 ? sqp[2*pp+1] : sqp[2*pp];
            float send = b0 ? sqp[2*pp]   : sqp[2*pp+1];
            fv8[pp] = keep + __shfl_xor(send, 1);
          }
        } else if (et == 1) {
#pragma unroll
          for (int pp = 0; pp < 4; ++pp) {
            float keep = b1 ? fv8[2*pp+1] : fv8[2*pp];
            float send = b1 ? fv8[2*pp]   : fv8[2*pp+1];
            fv4[pp] = keep + __shfl_xor(send, 2);
          }
        } else if (et == 2) {
#pragma unroll
          for (int pp = 0; pp < 2; ++pp) {
            float keep = b2 ? fv4[2*pp+1] : fv4[2*pp];
            float send = b2 ? fv4[2*pp]   : fv4[2*pp+1];
            fv2[pp] = keep + __shfl_xor(send, 4);
          }
        } else {
          float keep = b3 ? fv2[1] : fv2[0];
          float send = b3 ? fv2[0] : fv2[1];
          float z = keep + __shfl_xor(send, 8);
          float wv = fmaf(-0.5f, z, ckp);
          if (wv > best || (wv == best && kprev < bidx)) { best = wv; bidx = kprev; }
        }
      }

#pragma unroll
      for (int c = 0; c < 2; ++c) {
        // consecutive lanes -> consecutive 16B: 2-way bank aliasing (free)
        const char* bp = lb + ((et * 2 + c) << 11) + (lane << 4);
        f16x8 bh = *(const f16x8*)bp;
        f16x8 bl = *(const f16x8*)(bp + 1024);
#pragma unroll
        for (int rt = 0; rt < RT; ++rt) {
          acc[rt] = __builtin_amdgcn_mfma_f32_16x16x32_f16(ahi[rt][c], bh, acc[rt], 0, 0, 0);
          acc[rt] = __builtin_amdgcn_mfma_f32_16x16x32_f16(ahi[rt][c], bl, acc[rt], 0, 0, 0);
          acc[rt] = __builtin_amdgcn_mfma_f32_16x16x32_f16(alo[rt][c], bh, acc[rt], 0, 0, 0);
        }
      }
#pragma unroll
      for (int rt = 0; rt < RT; ++rt)
#pragma unroll
        for (int r = 0; r < 4; ++r)
          sq[rt * 4 + r] = fmaf(acc[rt][r], acc[rt][r], sq[rt * 4 + r]);
    }

    // stash this k's sums for the pipelined fold
#pragma unroll
    for (int i = 0; i < 16; ++i) sqp[i] = sq[i];
    ckp = ck;
    kprev = k;

    __syncthreads();   // next buffer's DMA drained; all waves done with buf p
  }

  // ---- tail fold for the last k ----
  {
#pragma unroll
    for (int pp = 0; pp < 8; ++pp) {
      float keep = b0 ? sqp[2*pp+1] : sqp[2*pp];
      float send = b0 ? sqp[2*pp]   : sqp[2*pp+1];
      fv8[pp] = keep + __shfl_xor(send, 1);
    }
#pragma unroll
    for (int pp = 0; pp < 4; ++pp) {
      float keep = b1 ? fv8[2*pp+1] : fv8[2*pp];
      float send = b1 ? fv8[2*pp]   : fv8[2*pp+1];
      fv4[pp] = keep + __shfl_xor(send, 2);
    }
#pragma unroll
    for (int pp = 0; pp < 2; ++pp) {
      float keep = b2 ? fv4[2*pp+1] : fv4[2*pp];
      float send = b2 ? fv4[2*pp]   : fv4[2*pp+1];
      fv2[pp] = keep + __shfl_xor(send, 4);
    }
    float keep = b3 ? fv2[1] : fv2[0];
    float send = b3 ? fv2[0] : fv2[1];
    float z = keep + __shfl_xor(send, 8);
    float wv = fmaf(-0.5f, z, ckp);
    if (wv > best || (wv == best && kprev < bidx)) { best = wv; bidx = kprev; }
  }

  // ---- publish per-row best via one atomicMax(u64), all 64 lanes ----
  // key: monotone(float) high 32 bits, (63-k) low -> max == argmax with
  // first-max (min-k) tie-break, matching jnp.argmax.
  {
    int row = rowbase + (m >> 2) * 16 + q * 4 + (m & 3);
    unsigned int b = __float_as_uint(best);
    unsigned int u = (b & 0x80000000u) ? ~b : (b | 0x80000000u);
    unsigned long long pkd = ((unsigned long long)u << 32)
                           | (unsigned long long)(63 - bidx);
    atomicMax(&packed[row], pkd);
  }
  __builtin_amdgcn_s_waitcnt(0);   // atomics ack'd at coherent point (local op)
  __syncthreads();
  if (tid == 0) {
    int old = atomicAdd(&cnt[blockIdx.x], 1);
    is_last = (old == KSPLIT - 1);
  }
  __syncthreads();
  if (is_last) {
    int n = blockIdx.x * ROWS_PER_BLOCK + tid;
    unsigned long long pv = __hip_atomic_load(&packed[n], __ATOMIC_RELAXED,
                                              __HIP_MEMORY_SCOPE_AGENT);
    out[n] = 63 - (int)(pv & 63ull);
  }
}

extern "C" void kernel_launch(void* const* d_in, const int* in_sizes, int n_in,
                              void* d_out, int out_size, void* d_ws, size_t ws_size,
                              hipStream_t stream) {
  const float* X     = (const float*)d_in[0];
  const float* means = (const float*)d_in[1];
  const float* P     = (const float*)d_in[2];
  const float* wc    = (const float*)d_in[3];
  const float* dof   = (const float*)d_in[4];
  const float* mp    = (const float*)d_in[5];
  int* out = (int*)d_out;

  // workspace layout (bytes):
  // [0,16384)           muP (4096 f32)
  // [16640,17152)       t_arr (64 f64)
  // [17152,17664)       g_arr
  // [17664,18176)       pc_arr
  // [20480,21504)       cnt (<=256 i32)
  // [24576,286720)      packed (32768 u64)
  // [294912, +1048576)  Pt (64 k * 16384 B)
  char* wsb = (char*)d_ws;
  float*  muP    = (float*)(wsb);
  double* t_arr  = (double*)(wsb + 16640);
  double* g_arr  = (double*)(wsb + 17152);
  double* pc_arr = (double*)(wsb + 17664);
  int*    cnt    = (int*)(wsb + 20480);
  unsigned long long* packed = (unsigned long long*)(wsb + 24576);
  char*   Pt     = wsb + 294912;

  prep1_kernel<<<KCOMP, PREP_THREADS, 0, stream>>>(means, P, wc, dof, mp, Pt,
                                                   muP, t_arr, g_arr, pc_arr,
                                                   (uint4*)packed, (uint4*)cnt);

  dim3 grid(ROWGROUPS, KSPLIT);
  main_kernel<<<grid, THREADS, 0, stream>>>(X, Pt, muP, t_arr, g_arr, pc_arr,
                                            packed, cnt, out);
}

// Round 15
// 113.650 us; speedup vs baseline: 2.3480x; 2.3480x over previous
//
#include <hip/hip_runtime.h>
#include <math.h>

#define N_ROWS 32768
#define DIM 64
#define KCOMP 64
#define KSPLIT 8
#define KLOCAL 8           // KCOMP / KSPLIT
#define THREADS 256        // 4 waves
#define PREP_THREADS 256
#define RT 4               // row-tiles of 16 per wave
#define ROWS_PER_WAVE 64
#define ROWS_PER_BLOCK 256 // 4 waves * 64 rows
#define ROWGROUPS (N_ROWS / ROWS_PER_BLOCK)   // 128

// Pt layout per k (16384 B total, no padding):
//   for et in 0..4, c in 0..2:  block of 2048 B at (et*2+c)*2048:
//     [hi: 64 chunks x 16 B, chunk index = lane = q*16+m]
//     [lo: same, +1024]
//   chunk(lane) holds f16 P[d = c*32 + q*8 + j][e = et*16 + m], j=0..7
#define PT_K_BYTES 16384

#define LOG2PI_D 1.8378770664093454836

typedef _Float16 f16x8 __attribute__((ext_vector_type(8)));
typedef float f32x4 __attribute__((ext_vector_type(4)));

#define AS1 __attribute__((address_space(1)))
#define AS3 __attribute__((address_space(3)))

// async 16B/lane global->LDS DMA: lds dest wave-uniform; lane i -> base+i*16
__device__ __forceinline__ void async_copy16(const char* g, char* l) {
  __builtin_amdgcn_global_load_lds((const AS1 unsigned int*)g,
                                   (AS3 unsigned int*)l, 16, 0, 0);
}

// ---------------- digamma (double, recurrence + asymptotic) ----------------
__device__ __forceinline__ double digamma_d(double x) {
  double r = 0.0;
  while (x < 6.0) { r -= 1.0 / x; x += 1.0; }
  double inv = 1.0 / x;
  double inv2 = inv * inv;
  double s = log(x) - 0.5 * inv
      - inv2 * (1.0/12.0 - inv2 * (1.0/120.0 - inv2 * (1.0/252.0
      - inv2 * (1.0/240.0 - inv2 * (1.0/132.0)))));
  return r + s;
}

// ------- prep1: one block per k. LDS-staged transpose repack of P into Pt.
//         Wave 0: muP, log-det, digamma sums, stick-breaking terms.
//         Also zeroes packed/cnt (fused memset -> one fewer graph node). ----
__global__ void prep1_kernel(const float* __restrict__ means,
                             const float* __restrict__ P,
                             const float* __restrict__ wc,
                             const float* __restrict__ dof,
                             const float* __restrict__ mp,
                             char*   __restrict__ Pt,
                             float*  __restrict__ muP,
                             double* __restrict__ t_arr,
                             double* __restrict__ g_arr,
                             double* __restrict__ pc_arr,
                             uint4*  __restrict__ packed4,  // 16384 x 16 B
                             uint4*  __restrict__ cnt4)     // 64 x 16 B
{
  __shared__ float lds[DIM][DIM + 1];
  const int k = blockIdx.x;
  const int t = threadIdx.x;
  const float* Pk = P + k * DIM * DIM;

  // fused memset: zero packed (64 blk x 256 thr x 16 B = 256 KB) + cnt
  const uint4 z4 = {0u, 0u, 0u, 0u};
  packed4[k * PREP_THREADS + t] = z4;
  if (k == 0 && t < 64) cnt4[t] = z4;

  for (int i = t; i < DIM * DIM; i += PREP_THREADS)
    lds[i >> 6][i & 63] = Pk[i];
  __syncthreads();

  char* dst = Pt + (size_t)k * PT_K_BYTES;
#pragma unroll
  for (int cc = 0; cc < 4; ++cc) {
    int cid  = cc * PREP_THREADS + t;
    int blk  = cid >> 7;               // et*2 + c
    int sel  = (cid >> 6) & 1;         // 0=hi 1=lo
    int lane = cid & 63;
    int et = blk >> 1, c = blk & 1;
    int m = lane & 15, q = lane >> 4;
    int e = et * 16 + m;
    int d0 = c * 32 + q * 8;
    f16x8 o;
#pragma unroll
    for (int j = 0; j < 8; ++j) {
      float v = lds[d0 + j][e];
      _Float16 h = (_Float16)v;
      o[j] = sel ? (_Float16)(v - (float)h) : h;
    }
    *(f16x8*)(dst + cid * 16) = o;
  }

  if (t < 64) {
    const int i = t;
    const float* mk = means + k * DIM;
    float acc = 0.f;
#pragma unroll 8
    for (int d = 0; d < DIM; ++d) acc = fmaf(mk[d], lds[d][i], acc);
    muP[k * DIM + i] = acc;

    double dofk = (double)dof[k];
    double s1 = digamma_d(0.5 * (dofk - (double)i));
    double s2 = log((double)lds[i][i]);
#pragma unroll
    for (int off = 32; off > 0; off >>= 1) {
      s1 += __shfl_down(s1, off);
      s2 += __shfl_down(s2, off);
    }
    if (i == 0) {
      double ak = (double)wc[k], bk = (double)wc[KCOMP + k];
      double dgab = digamma_d(ak + bk);
      double log_lambda = (double)DIM * log(2.0) + s1;
      double pc = s2
                - 0.5 * (double)DIM * LOG2PI_D
                - 0.5 * (double)DIM * log(dofk)
                + 0.5 * (log_lambda - (double)DIM / (double)mp[k]);
      t_arr[k] = digamma_d(bk) - dgab;
      g_arr[k] = digamma_d(ak) - dgab;
      pc_arr[k] = pc;
    }
  }
}

// -------- main: R13 structure (best measured: 48.2 us, no spill).
//          f16-split MFMA, 4 row-tiles/wave (64 rows), double-buffered LDS B
//          via async global_load_lds, 4-stage folded reduction inline (the
//          R14 pipelined fold spilled to scratch: 48->200 us). Fused argmax
//          via device-scope atomics, NO fences (R8: fences = cache-wide L2
//          maintenance -> chip-wide collapse). ------------------------------
__global__ __launch_bounds__(THREADS, 4) void main_kernel(
    const float* __restrict__ X,
    const char*  __restrict__ Pt,
    const float* __restrict__ muP,
    const double* __restrict__ t_arr,
    const double* __restrict__ g_arr,
    const double* __restrict__ pc_arr,
    unsigned long long* __restrict__ packed,  // [N_ROWS], zeroed by prep1
    int* __restrict__ cnt,                    // [ROWGROUPS], zeroed by prep1
    int* __restrict__ out)
{
  __shared__ uint4 bbuf[2][PT_K_BYTES / 16];  // 2 x 16 KB B double-buffer
  __shared__ float cvec_lds[KCOMP];
  __shared__ float mup_lds[KLOCAL * DIM];
  __shared__ int is_last;

  const int tid  = threadIdx.x;
  const int wave = tid >> 6;           // 0..3
  const int lane = tid & 63;
  const int m    = lane & 15;          // MFMA row (A) / col (B) index
  const int q    = lane >> 4;          // quad
  const int ks   = blockIdx.y;
  const int rowbase = blockIdx.x * ROWS_PER_BLOCK + wave * ROWS_PER_WAVE;
  const int k0   = ks * KLOCAL;

  // ---- kick off async stage of k0's B image into buf 0 (4 DMA insts/wave) --
  {
    const char* src = Pt + (size_t)k0 * PT_K_BYTES;
#pragma unroll
    for (int i = 0; i < 4; ++i) {
      const int g = wave * 4 + i;                    // 1 KB group, uniform/wave
      async_copy16(src + (g << 10) + (lane << 4),
                   (char*)&bbuf[0][g << 6]);
    }
  }

  // wave 0: stick-breaking prefix -> cvec in LDS (6 shuffles)
  if (tid < 64) {
    double t = t_arr[tid];
    double s = t;
#pragma unroll
    for (int off = 1; off < 64; off <<= 1) {
      double v = __shfl_up(s, off);
      if (tid >= off) s += v;
    }
    cvec_lds[tid] = (float)(pc_arr[tid] + g_arr[tid] + (s - t));
  }
  // stage this block's muP slice: [k_local][e], coalesced
  for (int i = tid; i < KLOCAL * DIM; i += THREADS)
    mup_lds[i] = muP[ks * KLOCAL * DIM + i];

  // ---- load + split X rows into register-resident A fragments (4 tiles) ----
  f16x8 ahi[RT][2], alo[RT][2];
#pragma unroll
  for (int rt = 0; rt < RT; ++rt) {
    int row = rowbase + rt * 16 + m;
    const float* xp = X + row * DIM;
#pragma unroll
    for (int c = 0; c < 2; ++c) {
      const float4* xq4 = (const float4*)(xp + c * 32 + q * 8);
      float4 v0 = xq4[0], v1 = xq4[1];
      float xv[8] = {v0.x, v0.y, v0.z, v0.w, v1.x, v1.y, v1.z, v1.w};
      f16x8 h, l;
#pragma unroll
      for (int j = 0; j < 8; ++j) {
        _Float16 hv = (_Float16)xv[j];
        h[j] = hv;
        l[j] = (_Float16)(xv[j] - (float)hv);
      }
      ahi[rt][c] = h;
      alo[rt][c] = l;
    }
  }

  __syncthreads();   // buf0 DMA drained (vmcnt) + cvec/mup visible

  float best = -INFINITY;
  int   bidx = 0;
  const bool b0 = (m & 1), b1 = (m & 2), b2 = (m & 4), b3 = (m & 8);

  for (int ki = 0; ki < KLOCAL; ++ki) {
    const int k = k0 + ki;
    const int p = ki & 1;

    // async stage next k's B into the other buffer (lands during compute)
    if (ki + 1 < KLOCAL) {
      const char* src = Pt + (size_t)(k + 1) * PT_K_BYTES;
#pragma unroll
      for (int i = 0; i < 4; ++i) {
        const int g = wave * 4 + i;
        async_copy16(src + (g << 10) + (lane << 4),
                     (char*)&bbuf[1 - p][g << 6]);
      }
    }

    const char* lb = (const char*)bbuf[p];
    const float ck = cvec_lds[k];
    float sq[16];
#pragma unroll
    for (int i = 0; i < 16; ++i) sq[i] = 0.f;      // idx = rt*4 + r

#pragma unroll
    for (int et = 0; et < 4; ++et) {
      const float mval = -mup_lds[(ki << 6) + et * 16 + m];
      f32x4 acc[RT];
#pragma unroll
      for (int rt = 0; rt < RT; ++rt)
#pragma unroll
        for (int r = 0; r < 4; ++r) acc[rt][r] = mval;

#pragma unroll
      for (int c = 0; c < 2; ++c) {
        // consecutive lanes -> consecutive 16B: 2-way bank aliasing (free)
        const char* bp = lb + ((et * 2 + c) << 11) + (lane << 4);
        f16x8 bh = *(const f16x8*)bp;
        f16x8 bl = *(const f16x8*)(bp + 1024);
#pragma unroll
        for (int rt = 0; rt < RT; ++rt) {
          acc[rt] = __builtin_amdgcn_mfma_f32_16x16x32_f16(ahi[rt][c], bh, acc[rt], 0, 0, 0);
          acc[rt] = __builtin_amdgcn_mfma_f32_16x16x32_f16(ahi[rt][c], bl, acc[rt], 0, 0, 0);
          acc[rt] = __builtin_amdgcn_mfma_f32_16x16x32_f16(alo[rt][c], bh, acc[rt], 0, 0, 0);
        }
      }
#pragma unroll
      for (int rt = 0; rt < RT; ++rt)
#pragma unroll
        for (int r = 0; r < 4; ++r)
          sq[rt * 4 + r] = fmaf(acc[rt][r], acc[rt][r], sq[rt * 4 + r]);
    }

    // folded reduction over 16 m-lanes: 16 values -> 1 per lane (id = m)
    float v8[8];
#pragma unroll
    for (int pp = 0; pp < 8; ++pp) {
      float keep = b0 ? sq[2*pp+1] : sq[2*pp];
      float send = b0 ? sq[2*pp]   : sq[2*pp+1];
      v8[pp] = keep + __shfl_xor(send, 1);
    }
    float v4[4];
#pragma unroll
    for (int pp = 0; pp < 4; ++pp) {
      float keep = b1 ? v8[2*pp+1] : v8[2*pp];
      float send = b1 ? v8[2*pp]   : v8[2*pp+1];
      v4[pp] = keep + __shfl_xor(send, 2);
    }
    float v2[2];
#pragma unroll
    for (int pp = 0; pp < 2; ++pp) {
      float keep = b2 ? v4[2*pp+1] : v4[2*pp];
      float send = b2 ? v4[2*pp]   : v4[2*pp+1];
      v2[pp] = keep + __shfl_xor(send, 4);
    }
    float keep = b3 ? v2[1] : v2[0];
    float send = b3 ? v2[0] : v2[1];
    float z = keep + __shfl_xor(send, 8);
    // lane m holds sum over e for value id m: rt = m>>2, r = m&3

    float wv = fmaf(-0.5f, z, ck);
    if (wv > best || (wv == best && k < bidx)) { best = wv; bidx = k; }

    __syncthreads();   // next buffer's DMA drained; all waves done with buf p
  }

  // ---- publish per-row best via one atomicMax(u64), all 64 lanes ----
  // key: monotone(float) high 32 bits, (63-k) low -> max == argmax with
  // first-max (min-k) tie-break, matching jnp.argmax.
  {
    int row = rowbase + (m >> 2) * 16 + q * 4 + (m & 3);
    unsigned int b = __float_as_uint(best);
    unsigned int u = (b & 0x80000000u) ? ~b : (b | 0x80000000u);
    unsigned long long pkd = ((unsigned long long)u << 32)
                           | (unsigned long long)(63 - bidx);
    atomicMax(&packed[row], pkd);
  }
  __builtin_amdgcn_s_waitcnt(0);   // atomics ack'd at coherent point (local op)
  __syncthreads();
  if (tid == 0) {
    int old = atomicAdd(&cnt[blockIdx.x], 1);
    is_last = (old == KSPLIT - 1);
  }
  __syncthreads();
  if (is_last) {
    int n = blockIdx.x * ROWS_PER_BLOCK + tid;
    unsigned long long pv = __hip_atomic_load(&packed[n], __ATOMIC_RELAXED,
                                              __HIP_MEMORY_SCOPE_AGENT);
    out[n] = 63 - (int)(pv & 63ull);
  }
}

extern "C" void kernel_launch(void* const* d_in, const int* in_sizes, int n_in,
                              void* d_out, int out_size, void* d_ws, size_t ws_size,
                              hipStream_t stream) {
  const float* X     = (const float*)d_in[0];
  const float* means = (const float*)d_in[1];
  const float* P     = (const float*)d_in[2];
  const float* wc    = (const float*)d_in[3];
  const float* dof   = (const float*)d_in[4];
  const float* mp    = (const float*)d_in[5];
  int* out = (int*)d_out;

  // workspace layout (bytes):
  // [0,16384)           muP (4096 f32)
  // [16640,17152)       t_arr (64 f64)
  // [17152,17664)       g_arr
  // [17664,18176)       pc_arr
  // [20480,21504)       cnt (<=256 i32)
  // [24576,286720)      packed (32768 u64)
  // [294912, +1048576)  Pt (64 k * 16384 B)
  char* wsb = (char*)d_ws;
  float*  muP    = (float*)(wsb);
  double* t_arr  = (double*)(wsb + 16640);
  double* g_arr  = (double*)(wsb + 17152);
  double* pc_arr = (double*)(wsb + 17664);
  int*    cnt    = (int*)(wsb + 20480);
  unsigned long long* packed = (unsigned long long*)(wsb + 24576);
  char*   Pt     = wsb + 294912;

  prep1_kernel<<<KCOMP, PREP_THREADS, 0, stream>>>(means, P, wc, dof, mp, Pt,
                                                   muP, t_arr, g_arr, pc_arr,
                                                   (uint4*)packed, (uint4*)cnt);

  dim3 grid(ROWGROUPS, KSPLIT);
  main_kernel<<<grid, THREADS, 0, stream>>>(X, Pt, muP, t_arr, g_arr, pc_arr,
                                            packed, cnt, out);
}